// Round 1
// baseline (961.634 us; speedup 1.0000x reference)
//
#include <hip/hip_runtime.h>

// SparseBPLinear: out[b, p*8+i] = sum_{q,l} x[b, q*8+l] * W[p,q,i,l]
//   W[p,q,i,l] = sum_j u[p,q,i,j] * s[p,q,j] * v[p,q,j,l]
// P=Q=1024, K=8, BS=64. All f32.
// One block per p; double-buffered LDS staging of u/s/v; W assembled in LDS
// per 16-q group; each thread accumulates out[b0, p*8+i] and out[b0+32, p*8+i].

#define PDIM 1024
#define QDIM 1024
#define KB   8
#define BSZ  64
#define GQ   16            // q's per group
#define NG   (QDIM / GQ)   // 64 groups

__global__ __launch_bounds__(256, 4)
void sbp_kernel(const float* __restrict__ x, const float* __restrict__ u,
                const float* __restrict__ s, const float* __restrict__ v,
                float* __restrict__ out)
{
    __shared__ float su[2][GQ * 64];   // [q][i][j]
    __shared__ float sv[2][GQ * 64];   // [q][j][l]
    __shared__ float ss[2][GQ * 8];    // [q][j]
    __shared__ float sw[GQ * 64];      // assembled W: [q][i][l]

    const int p = blockIdx.x;
    const int t = threadIdx.x;          // 0..255
    const int i  = t & 7;               // output column within p-block
    const int b0 = t >> 3;              // 0..31 ; second row is b0+32

    const size_t uvbase = (size_t)p * (QDIM * 64);
    const size_t sbase  = (size_t)p * (QDIM * 8);

    float4 pu, pv; float ps = 0.f;

    // ---- stage group 0 ----
    pu = *(const float4*)(u + uvbase + (size_t)t * 4);
    pv = *(const float4*)(v + uvbase + (size_t)t * 4);
    if (t < GQ * 8) ps = s[sbase + t];
    *(float4*)&su[0][t * 4] = pu;
    *(float4*)&sv[0][t * 4] = pv;
    if (t < GQ * 8) ss[0][t] = ps;
    __syncthreads();

    float acc0 = 0.f, acc1 = 0.f;

    // phase-A work assignment: 4 consecutive W entries per thread
    const int n0 = t * 4;
    const int qa = n0 >> 6;         // q within group
    const int ia = (n0 >> 3) & 7;   // i
    const int l0 = n0 & 7;          // 0 or 4

    for (int g = 0; g < NG; ++g) {
        const int cur = g & 1;

        // ---- issue prefetch of group g+1 (loads stay in flight) ----
        if (g + 1 < NG) {
            const size_t off = (size_t)(g + 1) * (GQ * 64);
            pu = *(const float4*)(u + uvbase + off + (size_t)t * 4);
            pv = *(const float4*)(v + uvbase + off + (size_t)t * 4);
            if (t < GQ * 8) ps = s[sbase + (size_t)(g + 1) * (GQ * 8) + t];
        }

        // ---- phase A: assemble W[qa][ia][l0..l0+3] ----
        {
            const float* bu = &su[cur][qa * 64 + ia * 8];
            const float* bs = &ss[cur][qa * 8];
            float4 u0 = *(const float4*)(bu);
            float4 u1 = *(const float4*)(bu + 4);
            float4 s0 = *(const float4*)(bs);
            float4 s1 = *(const float4*)(bs + 4);
            float us[8];
            us[0] = u0.x * s0.x; us[1] = u0.y * s0.y;
            us[2] = u0.z * s0.z; us[3] = u0.w * s0.w;
            us[4] = u1.x * s1.x; us[5] = u1.y * s1.y;
            us[6] = u1.z * s1.z; us[7] = u1.w * s1.w;
            const float* bv = &sv[cur][qa * 64 + l0];
            float wx = 0.f, wy = 0.f, wz = 0.f, ww = 0.f;
#pragma unroll
            for (int j = 0; j < 8; ++j) {
                float4 vv = *(const float4*)(bv + j * 8);
                wx += us[j] * vv.x; wy += us[j] * vv.y;
                wz += us[j] * vv.z; ww += us[j] * vv.w;
            }
            float4 w; w.x = wx; w.y = wy; w.z = wz; w.w = ww;
            *(float4*)&sw[qa * 64 + ia * 8 + l0] = w;
        }
        __syncthreads();   // sw ready

        // ---- phase B: accumulate 16 q's ----
        {
            const float* xr0 = x + (size_t)b0 * (QDIM * KB) + (size_t)g * (GQ * KB);
            const float* xr1 = xr0 + (size_t)32 * (QDIM * KB);
#pragma unroll 4
            for (int q = 0; q < GQ; ++q) {
                float4 xa = *(const float4*)(xr0 + q * 8);
                float4 xb = *(const float4*)(xr0 + q * 8 + 4);
                float4 xc = *(const float4*)(xr1 + q * 8);
                float4 xd = *(const float4*)(xr1 + q * 8 + 4);
                float4 wa = *(const float4*)(&sw[q * 64 + i * 8]);
                float4 wb = *(const float4*)(&sw[q * 64 + i * 8 + 4]);
                acc0 += xa.x * wa.x + xa.y * wa.y + xa.z * wa.z + xa.w * wa.w;
                acc0 += xb.x * wb.x + xb.y * wb.y + xb.z * wb.z + xb.w * wb.w;
                acc1 += xc.x * wa.x + xc.y * wa.y + xc.z * wa.z + xc.w * wa.w;
                acc1 += xd.x * wb.x + xd.y * wb.y + xd.z * wb.z + xd.w * wb.w;
            }
        }

        // ---- commit prefetched group into the other buffer ----
        if (g + 1 < NG) {
            const int nb = (g + 1) & 1;
            *(float4*)&su[nb][t * 4] = pu;
            *(float4*)&sv[nb][t * 4] = pv;
            if (t < GQ * 8) ss[nb][t] = ps;
        }
        __syncthreads();   // next buffer ready; sw consumers done
    }

    out[(size_t)b0 * (PDIM * KB) + (size_t)p * KB + i]        = acc0;
    out[(size_t)(b0 + 32) * (PDIM * KB) + (size_t)p * KB + i] = acc1;
}

extern "C" void kernel_launch(void* const* d_in, const int* in_sizes, int n_in,
                              void* d_out, int out_size, void* d_ws, size_t ws_size,
                              hipStream_t stream) {
    const float* x = (const float*)d_in[0];
    const float* u = (const float*)d_in[1];
    const float* s = (const float*)d_in[2];
    const float* v = (const float*)d_in[3];
    float* out = (float*)d_out;
    hipLaunchKernelGGL(sbp_kernel, dim3(PDIM), dim3(256), 0, stream,
                       x, u, s, v, out);
}